// Round 11
// baseline (101.095 us; speedup 1.0000x reference)
//
#include <hip/hip_runtime.h>
#include <math.h>

#define N 4096
#define E 96
#define H 6
#define DH 16
#define G 64
#define CMAX 128          // max supported group size (mean 64, +8 sigma safe)
#define KSTR 19           // LDS row stride for kh/vh/qh (r6/r10-proven)
#define FSTR 104          // bf16 elems per staged row (96 + 8 pad): 208 B, 16B-aligned
#define NW 8              // waves per block
#define NT 512            // threads per block

typedef __attribute__((ext_vector_type(8))) short short8;   // 8 bf16 in 4 VGPRs
typedef __attribute__((ext_vector_type(4))) float f32x4;

static __device__ __forceinline__ unsigned short f2bf(float f) {
    unsigned u = __builtin_bit_cast(unsigned, f);
    return (unsigned short)((u + 0x7fffu + ((u >> 16) & 1u)) >> 16);   // RNE
}
static __device__ __forceinline__ unsigned pack2(float lo, float hi) {
    return (unsigned)f2bf(lo) | ((unsigned)f2bf(hi) << 16);
}

// One block per (group, head) — 384 blocks, all co-resident (2/CU LDS limit).
// bf16-MFMA qkv (r10-verified), deterministic bucket build (r6-verified),
// attention processes 2 rows/iteration with shared kh/vh reads + interleaved
// reduction chains (2x ILP, 0.5x LDS traffic vs 1-row loop).
__global__ __launch_bounds__(NT, 4) void fused_kernel(const float* __restrict__ feats,
                                                      const int* __restrict__ grp,
                                                      const float* __restrict__ w_in,
                                                      const float* __restrict__ b_in,
                                                      const float* __restrict__ w_out,
                                                      const float* __restrict__ w_cls,
                                                      float* __restrict__ part) {
    __shared__ short fA[CMAX * FSTR];     // 26.6 KB staged feats rows (bf16)
    __shared__ short wB[48 * FSTR];       // 10 KB w_in head slice (bf16)
    __shared__ float bia[48];
    __shared__ float kh[CMAX * KSTR];
    __shared__ float vh[CMAX * KSTR];     // zero-filled; rows < cnt overwritten
    __shared__ float qh[CMAX * KSTR];     // all q rows (no parity split)
    __shared__ float ps[NW * 2 * CMAX];   // per-wave softmax weights, 2 rows in flight
    __shared__ int   bucket[CMAX];
    __shared__ unsigned long long smask[64];
    __shared__ int   scount[64];
    __shared__ int   soffs[64];
    __shared__ float wfh[DH];             // head slice of folded classifier
    __shared__ int   scnt;

    int g = blockIdx.x & 63;
    int h = blockIdx.x >> 6;              // 0..5
    int tid = threadIdx.x, lane = tid & 63, wv = tid >> 6;

    // ---- Phase A: per-chunk ballot masks (deterministic)
    #pragma unroll
    for (int c8 = 0; c8 < 8; ++c8) {
        int cc = wv * 8 + c8;
        bool mt = (grp[(cc << 6) + lane] == g);
        unsigned long long mask = __ballot(mt);
        if (lane == 0) { smask[cc] = mask; scount[cc] = __popcll(mask); }
    }

    // ---- stage wB (bf16) + bia + wfh (disjoint thread ranges)
    if (tid < 384) {
        int row = tid >> 3, seg = tid & 7;          // row = part*16 + dd, seg: 12 floats
        int gcol = (row >> 4) * E + h * DH + (row & 15);
        const float4* src = (const float4*)(w_in + gcol * E + seg * 12);
        unsigned* dst = (unsigned*)(wB + row * FSTR + seg * 12);
        #pragma unroll
        for (int t = 0; t < 3; ++t) {
            float4 v = src[t];
            dst[2 * t]     = pack2(v.x, v.y);
            dst[2 * t + 1] = pack2(v.z, v.w);
        }
    } else if (tid < 432) {
        int c = tid - 384;
        bia[c] = b_in[(c >> 4) * E + h * DH + (c & 15)];
    } else if (wv == 7) {
        int dd = lane & 15, u4 = lane >> 4;
        float s = 0.f;
        for (int u = u4 * 24; u < u4 * 24 + 24; ++u)
            s += w_cls[u] * w_out[u * E + h * DH + dd];
        s += __shfl_xor(s, 16, 64);
        s += __shfl_xor(s, 32, 64);
        if (lane < DH) wfh[lane] = s;
    }
    __syncthreads();

    // ---- Phase B: wave 0 scans chunk counts; waves 1..7 zero-fill vh
    if (wv == 0) {
        int v = scount[lane];
        int x = v;
        #pragma unroll
        for (int o = 1; o < 64; o <<= 1) {
            int y = __shfl_up(x, o, 64);
            if (lane >= o) x += y;
        }
        soffs[lane] = x - v;
        if (lane == 63) scnt = x;
    } else {
        for (int idx = tid - 64; idx < CMAX * KSTR; idx += NT - 64) vh[idx] = 0.f;
    }
    __syncthreads();

    int cnt = scnt; if (cnt > CMAX) cnt = CMAX;

    // ---- Phase C: deterministic scatter
    #pragma unroll
    for (int c8 = 0; c8 < 8; ++c8) {
        int cc = wv * 8 + c8;
        unsigned long long mask = smask[cc];
        if ((mask >> lane) & 1ULL) {
            int pos = soffs[cc] + __popcll(mask & ((1ULL << lane) - 1ULL));
            if (pos < CMAX) bucket[pos] = (cc << 6) + lane;
        }
    }
    __syncthreads();

    // ---- stage fA: group's feats rows as bf16 (6 float4 loads per thread)
    {
        int srow = tid >> 2, sq = tid & 3;          // row, quarter (24 floats)
        if (srow < cnt) {
            const float4* src = (const float4*)(feats + bucket[srow] * E + sq * 24);
            unsigned* dst = (unsigned*)(fA + srow * FSTR + sq * 24);
            #pragma unroll
            for (int t = 0; t < 6; ++t) {
                float4 v = src[t];
                dst[2 * t]     = pack2(v.x, v.y);
                dst[2 * t + 1] = pack2(v.z, v.w);
            }
        }
    }
    __syncthreads();

    // ---- MFMA qkv: jobs (rt, ct); D col=lane&15, row=(lane>>4)*4+r (m89-verified)
    {
        int lr = lane & 15, kg = lane >> 4;
        int njobs = ((cnt + 15) >> 4) * 3;
        for (int jj = wv; jj < njobs; jj += NW) {
            int rt = jj / 3;
            int ct = jj - rt * 3;                   // 0=q 1=k 2=v
            const short* ab = fA + (rt * 16 + lr) * FSTR + kg * 8;
            const short* bb = wB + (ct * 16 + lr) * FSTR + kg * 8;
            f32x4 acc = {0.f, 0.f, 0.f, 0.f};
            acc = __builtin_amdgcn_mfma_f32_16x16x32_bf16(*(const short8*)(ab),
                                                          *(const short8*)(bb), acc, 0, 0, 0);
            acc = __builtin_amdgcn_mfma_f32_16x16x32_bf16(*(const short8*)(ab + 32),
                                                          *(const short8*)(bb + 32), acc, 0, 0, 0);
            acc = __builtin_amdgcn_mfma_f32_16x16x32_bf16(*(const short8*)(ab + 64),
                                                          *(const short8*)(bb + 64), acc, 0, 0, 0);
            float bias = bia[ct * 16 + lr];
            #pragma unroll
            for (int r = 0; r < 4; ++r) {
                int row = rt * 16 + kg * 4 + r;
                if (row < cnt) {
                    float v = acc[r] + bias;
                    if (ct == 1)      kh[row * KSTR + lr] = v;
                    else if (ct == 2) vh[row * KSTR + lr] = v;
                    else              qh[row * KSTR + lr] = v * 0.25f;
                }
            }
        }
    }
    __syncthreads();

    // ---- attention: 2 rows per iteration, shared K/V reads, interleaved chains
    float* ps0 = ps + (2 * wv) * CMAX;
    float* ps1 = ps + (2 * wv + 1) * CMAX;
    for (int j0 = wv; j0 < cnt; j0 += 2 * NW) {
        int j1 = j0 + NW;
        bool has1 = (j1 < cnt);
        int j1r = has1 ? j1 : j0;

        float qv0[16], qv1[16];
        #pragma unroll
        for (int e = 0; e < 16; ++e) {
            qv0[e] = qh[j0 * KSTR + e];             // broadcast reads
            qv1[e] = qh[j1r * KSTR + e];
        }

        float a00 = 0.f, a10 = 0.f;
        #pragma unroll
        for (int e = 0; e < 16; ++e) {
            float kl = kh[lane * KSTR + e];         // shared between both rows
            a00 += qv0[e] * kl;
            a10 += qv1[e] * kl;
        }
        float s00 = (lane < cnt) ? a00 : -INFINITY;
        float s10 = (lane < cnt) ? a10 : -INFINITY;
        float s01 = -INFINITY, s11 = -INFINITY;
        if (cnt > 64) {
            float a01 = 0.f, a11 = 0.f;
            #pragma unroll
            for (int e = 0; e < 16; ++e) {
                float kl = kh[(64 + lane) * KSTR + e];
                a01 += qv0[e] * kl;
                a11 += qv1[e] * kl;
            }
            s01 = (64 + lane < cnt) ? a01 : -INFINITY;
            s11 = (64 + lane < cnt) ? a11 : -INFINITY;
        }

        float m0 = fmaxf(s00, s01), m1 = fmaxf(s10, s11);
        #pragma unroll
        for (int o = 32; o >= 1; o >>= 1) {
            m0 = fmaxf(m0, __shfl_xor(m0, o, 64));
            m1 = fmaxf(m1, __shfl_xor(m1, o, 64));
        }
        float p00 = __expf(s00 - m0), p10 = __expf(s10 - m1);
        float p01 = (cnt > 64) ? __expf(s01 - m0) : 0.f;
        float p11 = (cnt > 64) ? __expf(s11 - m1) : 0.f;
        float l0 = p00 + p01, l1 = p10 + p11;
        #pragma unroll
        for (int o = 32; o >= 1; o >>= 1) {
            l0 += __shfl_xor(l0, o, 64);
            l1 += __shfl_xor(l1, o, 64);
        }
        ps0[lane] = p00; ps0[64 + lane] = p01;
        ps1[lane] = p10; ps1[64 + lane] = p11;
        // same-wave write->read: compiler inserts lgkmcnt wait; no barrier needed

        int mm4 = lane >> 4, dd = lane & 15;
        float acc0 = 0.f, acc1 = 0.f;
        #pragma unroll
        for (int k = 0; k < 16; ++k) {
            int m2 = mm4 + 4 * k;
            float vv = vh[m2 * KSTR + dd];          // shared between both rows
            acc0 += ps0[m2] * vv;
            acc1 += ps1[m2] * vv;
        }
        if (cnt > 64) {
            #pragma unroll
            for (int k = 16; k < 32; ++k) {
                int m2 = mm4 + 4 * k;
                float vv = vh[m2 * KSTR + dd];
                acc0 += ps0[m2] * vv;
                acc1 += ps1[m2] * vv;
            }
        }
        acc0 += __shfl_xor(acc0, 16, 64); acc1 += __shfl_xor(acc1, 16, 64);
        acc0 += __shfl_xor(acc0, 32, 64); acc1 += __shfl_xor(acc1, 32, 64);

        float pt0 = (acc0 / l0) * wfh[dd];
        float pt1 = (acc1 / l1) * wfh[dd];
        pt0 += __shfl_xor(pt0, 1, 64);  pt1 += __shfl_xor(pt1, 1, 64);
        pt0 += __shfl_xor(pt0, 2, 64);  pt1 += __shfl_xor(pt1, 2, 64);
        pt0 += __shfl_xor(pt0, 4, 64);  pt1 += __shfl_xor(pt1, 4, 64);
        pt0 += __shfl_xor(pt0, 8, 64);  pt1 += __shfl_xor(pt1, 8, 64);
        if (lane == 0) {
            part[bucket[j0] * 8 + h] = pt0;         // exactly-once writes, no atomic
            if (has1) part[bucket[j1] * 8 + h] = pt1;
        }
    }
}

// ---------------- K2: sum 6 head partials + folded bias, sigmoid
__global__ __launch_bounds__(512) void sigmoid_kernel(const float* __restrict__ part,
                                                      const float* __restrict__ w_cls,
                                                      const float* __restrict__ b_out,
                                                      const float* __restrict__ b_cls,
                                                      float* __restrict__ out) {
    __shared__ float sbias;
    int tid = threadIdx.x;
    if (tid < 64) {
        float s = w_cls[tid] * b_out[tid];
        if (tid < 32) s += w_cls[tid + 64] * b_out[tid + 64];
        #pragma unroll
        for (int o = 32; o >= 1; o >>= 1) s += __shfl_xor(s, o, 64);
        if (tid == 0) sbias = s + b_cls[0];
    }
    __syncthreads();
    int i = blockIdx.x * 512 + tid;
    const float4* p = (const float4*)(part + i * 8);
    float4 u = p[0], v = p[1];
    float s = u.x + u.y + u.z + u.w + v.x + v.y + sbias;
    out[i] = 1.f / (1.f + __expf(-s));
}

extern "C" void kernel_launch(void* const* d_in, const int* in_sizes, int n_in,
                              void* d_out, int out_size, void* d_ws, size_t ws_size,
                              hipStream_t stream) {
    const float* feats = (const float*)d_in[0];
    const int*   grp   = (const int*)  d_in[1];
    const float* w_in  = (const float*)d_in[2];
    const float* b_in  = (const float*)d_in[3];
    const float* w_out = (const float*)d_in[4];
    const float* b_out = (const float*)d_in[5];
    const float* w_cls = (const float*)d_in[6];
    const float* b_cls = (const float*)d_in[7];
    float* out = (float*)d_out;

    float* part = (float*)d_ws;           // N*8 floats, every (row,head<6) slot written

    fused_kernel<<<G * H, NT, 0, stream>>>(feats, grp, w_in, b_in, w_out, w_cls, part);
    sigmoid_kernel<<<N / 512, 512, 0, stream>>>(part, w_cls, b_out, b_cls, out);
}